// Round 10
// baseline (21.012 us; speedup 1.0000x reference)
//
#include <hip/hip_runtime.h>
#include <hip/hip_fp16.h>

// TensorCPFactorization: value[b] = sum_r prod_i f_i[idx[b,i], r]
// DIM=512, RANK=256, ORDER=4, BATCH=100000, f32 factors.
//
// R10: R9 + EPW 8->16 (amortize idx/store to 2 vmem instrs per 16 elems,
// halve wave count). Cost model (fit R0-R9): TA-serialized ~46clk per
// 2-segment wave-load, ~33 for 1-seg, independent of bytes. Gather floor =
// 200k 2-seg loads (2 f16 rows each) ~= 15.5us; + convert 0.7 + graph gap
// ~2.5. Two-phase register reuse keeps VGPR ~R9 level (TA-bound, so
// serializing the two halves is free).

#define DIM    512
#define RANK   256
#define FELEMS (DIM * RANK)
#define EPW    16

// ---- pass 1: f32 -> f16 conversion into d_ws ------------------------------
__global__ __launch_bounds__(256) void cp_convert_f16(
    const float* __restrict__ f0, const float* __restrict__ f1,
    const float* __restrict__ f2, const float* __restrict__ f3,
    __half* __restrict__ ws)
{
    const float* srcs[4] = {f0, f1, f2, f3};
    const float* __restrict__ src = srcs[blockIdx.y];
    __half* __restrict__ dst = ws + (size_t)blockIdx.y * FELEMS;

    const int base = (blockIdx.x * 256 + threadIdx.x) * 8;
    if (base >= FELEMS) return;

    const float4 a = *reinterpret_cast<const float4*>(src + base);
    const float4 b = *reinterpret_cast<const float4*>(src + base + 4);
    union { uint4 u; __half2 h[4]; } pk;
    pk.h[0] = __float22half2_rn(make_float2(a.x, a.y));
    pk.h[1] = __float22half2_rn(make_float2(a.z, a.w));
    pk.h[2] = __float22half2_rn(make_float2(b.x, b.y));
    pk.h[3] = __float22half2_rn(make_float2(b.z, b.w));
    *reinterpret_cast<uint4*>(dst + base) = pk.u;
}

// ---- pass 2: gather + dot over f16 rows -----------------------------------
__device__ __forceinline__ void cvt8(const uint4 u, float* v) {
    const __half2* h = reinterpret_cast<const __half2*>(&u);
    float2 t;
    t = __half22float2(h[0]); v[0] = t.x; v[1] = t.y;
    t = __half22float2(h[1]); v[2] = t.x; v[3] = t.y;
    t = __half22float2(h[2]); v[4] = t.x; v[5] = t.y;
    t = __half22float2(h[3]); v[6] = t.x; v[7] = t.y;
}

__global__ __launch_bounds__(256) void cp_gather_f16(
    const __half* __restrict__ wsh, const int* __restrict__ idx,
    float* __restrict__ out, int batch)
{
    __shared__ alignas(16) int   sidx[4][64];
    __shared__ alignas(16) float sout[4][16];

    const int l    = (int)(threadIdx.x & 63);
    const int slot = (int)(threadIdx.x >> 6);
    const int h    = l >> 5;          // which element of each pair
    const int l5   = l & 31;
    const int r0   = l5 * 8;
    const int wv   = blockIdx.x * 4 + slot;
    const int e0   = wv * EPW;
    if (e0 >= batch) return;
    const int lim = batch * 4 - 1;

    // one coalesced idx load per wave (64 lanes, one 256B segment) -> LDS
    {
        int ia = e0 * 4 + l;
        ia = ia < lim ? ia : lim;
        sidx[slot][l] = idx[ia];
    }
    // same-wave DS write->read: in-order per wave (validated R8/R9)

    float s[8];

    // two phases of 8 elements each; raw[] registers reused across phases
    #pragma unroll
    for (int ph = 0; ph < 2; ++ph) {
        int4 iv[4];
        #pragma unroll
        for (int p = 0; p < 4; ++p)
            iv[p] = *reinterpret_cast<const int4*>(&sidx[slot][ph * 32 + (2 * p + h) * 4]);

        // 16 dwordx4 loads, each covering 2 f16 rows (one per half-wave)
        uint4 raw[4][4];
        #pragma unroll
        for (int p = 0; p < 4; ++p) {
            raw[p][0] = *reinterpret_cast<const uint4*>(wsh + 0 * FELEMS + (size_t)iv[p].x * RANK + r0);
            raw[p][1] = *reinterpret_cast<const uint4*>(wsh + 1 * FELEMS + (size_t)iv[p].y * RANK + r0);
            raw[p][2] = *reinterpret_cast<const uint4*>(wsh + 2 * FELEMS + (size_t)iv[p].z * RANK + r0);
            raw[p][3] = *reinterpret_cast<const uint4*>(wsh + 3 * FELEMS + (size_t)iv[p].w * RANK + r0);
        }

        #pragma unroll
        for (int p = 0; p < 4; ++p) {
            float va[8], vb[8], vc[8], vd[8];
            cvt8(raw[p][0], va);
            cvt8(raw[p][1], vb);
            cvt8(raw[p][2], vc);
            cvt8(raw[p][3], vd);
            float acc = 0.f;
            #pragma unroll
            for (int k = 0; k < 8; ++k)
                acc += va[k] * vb[k] * vc[k] * vd[k];
            s[ph * 4 + p] = acc;
        }
    }

    // 5-step butterfly within each 32-lane half (8 independent chains)
    #pragma unroll
    for (int off = 16; off > 0; off >>= 1) {
        #pragma unroll
        for (int p = 0; p < 8; ++p)
            s[p] += __shfl_xor(s[p], off);
    }

    // repack via LDS -> one coalesced 16-lane store (64B segment)
    if (l5 == 0) {
        #pragma unroll
        for (int ph = 0; ph < 2; ++ph)
            #pragma unroll
            for (int p = 0; p < 4; ++p)
                sout[slot][ph * 8 + 2 * p + h] = s[ph * 4 + p];
    }
    if (l < 16) {
        const int e = e0 + l;
        if (e < batch) out[e] = sout[slot][l];
    }
}

// ---- fallback: R2 f32 direct gather (proven 21.4us) -----------------------
__global__ __launch_bounds__(256) void cp_gather_f32(
    const float* __restrict__ f0, const float* __restrict__ f1,
    const float* __restrict__ f2, const float* __restrict__ f3,
    const int*   __restrict__ idx,
    float*       __restrict__ out, int batch)
{
    const int wid  = (int)((blockIdx.x * blockDim.x + threadIdx.x) >> 6);
    const int lane = (int)(threadIdx.x & 63);
    const int e0   = wid * 4;
    if (e0 >= batch) return;
    const int r = lane * 4;
    float s[4];
    #pragma unroll
    for (int e = 0; e < 4; ++e) {
        const int  ec = (e0 + e) < batch ? (e0 + e) : batch - 1;
        const int4 iv = *reinterpret_cast<const int4*>(idx + (size_t)ec * 4);
        const float4 a = *reinterpret_cast<const float4*>(f0 + (size_t)iv.x * RANK + r);
        const float4 b = *reinterpret_cast<const float4*>(f1 + (size_t)iv.y * RANK + r);
        const float4 c = *reinterpret_cast<const float4*>(f2 + (size_t)iv.z * RANK + r);
        const float4 d = *reinterpret_cast<const float4*>(f3 + (size_t)iv.w * RANK + r);
        s[e] = a.x * b.x * c.x * d.x + a.y * b.y * c.y * d.y
             + a.z * b.z * c.z * d.z + a.w * b.w * c.w * d.w;
    }
    #pragma unroll
    for (int off = 32; off > 0; off >>= 1)
        #pragma unroll
        for (int e = 0; e < 4; ++e)
            s[e] += __shfl_xor(s[e], off);
    if (lane == 0)
        #pragma unroll
        for (int e = 0; e < 4; ++e)
            if (e0 + e < batch) out[e0 + e] = s[e];
}

extern "C" void kernel_launch(void* const* d_in, const int* in_sizes, int n_in,
                              void* d_out, int out_size, void* d_ws, size_t ws_size,
                              hipStream_t stream) {
    const float* f0  = (const float*)d_in[0];
    const float* f1  = (const float*)d_in[1];
    const float* f2  = (const float*)d_in[2];
    const float* f3  = (const float*)d_in[3];
    const int*   idx = (const int*)d_in[4];
    float* out = (float*)d_out;
    const int batch = out_size;

    const size_t ws_needed = (size_t)4 * FELEMS * sizeof(__half);  // 1 MiB
    if (ws_size >= ws_needed && batch >= 4) {
        __half* wsh = (__half*)d_ws;
        cp_convert_f16<<<dim3(FELEMS / (256 * 8), 4), 256, 0, stream>>>(f0, f1, f2, f3, wsh);
        const int waves = (batch + EPW - 1) / EPW;          // 6250
        const int grid  = (waves + 3) / 4;                  // 4 waves/block
        cp_gather_f16<<<grid, 256, 0, stream>>>(wsh, idx, out, batch);
    } else {
        const int grid = (batch + 15) / 16;
        cp_gather_f32<<<grid, 256, 0, stream>>>(f0, f1, f2, f3, idx, out, batch);
    }
}

// Round 11
// 19.637 us; speedup vs baseline: 1.0700x; 1.0700x over previous
//
#include <hip/hip_runtime.h>
#include <hip/hip_fp16.h>

// TensorCPFactorization: value[b] = sum_r prod_i f_i[idx[b,i], r]
// DIM=512, RANK=256, ORDER=4, BATCH=100000, f32 factors.
//
// R11 = R9 REVERT (best measured: 19.73us). R10's EPW=16 regressed (21.0):
// unrolled dual phases doubled in-flight raw[] VGPRs and halved wave-count
// TLP for a <0.5us theoretical gain.
//
// Structure (validated R0-R10):
//  k1: convert f32 factors -> f16 tables in d_ws.
//  k2: gather, wave64 per 8 elems; 16 dwordx4 loads each covering two 512B
//      f16 rows; idx via 1 coalesced 128B load + LDS distribution; output
//      via LDS repack + 1 coalesced 32B store.
// Cost model (fit R0-R10): TA-serialized ~33clk per 1-seg wave-load,
// ~46clk per 2-seg, INDEPENDENT OF BYTES (R3 nt-null, R5 half-bytes-null).
// Floor: 200k 2-seg loads ~15.5-16.5us + convert 0.7 + graph gap ~2.5.
// Escape routes closed: fp8/int8 accuracy (subnormal/threshold), LDS-gather
// (staging pays same TA cost, R6/R7), cooperative fusion (~85us spin, R8).

#define DIM    512
#define RANK   256
#define FELEMS (DIM * RANK)
#define EPW    8

// ---- pass 1: f32 -> f16 conversion into d_ws ------------------------------
__global__ __launch_bounds__(256) void cp_convert_f16(
    const float* __restrict__ f0, const float* __restrict__ f1,
    const float* __restrict__ f2, const float* __restrict__ f3,
    __half* __restrict__ ws)
{
    const float* srcs[4] = {f0, f1, f2, f3};
    const float* __restrict__ src = srcs[blockIdx.y];
    __half* __restrict__ dst = ws + (size_t)blockIdx.y * FELEMS;

    const int base = (blockIdx.x * 256 + threadIdx.x) * 8;
    if (base >= FELEMS) return;

    const float4 a = *reinterpret_cast<const float4*>(src + base);
    const float4 b = *reinterpret_cast<const float4*>(src + base + 4);
    union { uint4 u; __half2 h[4]; } pk;
    pk.h[0] = __float22half2_rn(make_float2(a.x, a.y));
    pk.h[1] = __float22half2_rn(make_float2(a.z, a.w));
    pk.h[2] = __float22half2_rn(make_float2(b.x, b.y));
    pk.h[3] = __float22half2_rn(make_float2(b.z, b.w));
    *reinterpret_cast<uint4*>(dst + base) = pk.u;
}

// ---- pass 2: gather + dot over f16 rows -----------------------------------
__device__ __forceinline__ void cvt8(const uint4 u, float* v) {
    const __half2* h = reinterpret_cast<const __half2*>(&u);
    float2 t;
    t = __half22float2(h[0]); v[0] = t.x; v[1] = t.y;
    t = __half22float2(h[1]); v[2] = t.x; v[3] = t.y;
    t = __half22float2(h[2]); v[4] = t.x; v[5] = t.y;
    t = __half22float2(h[3]); v[6] = t.x; v[7] = t.y;
}

__global__ __launch_bounds__(256) void cp_gather_f16(
    const __half* __restrict__ wsh, const int* __restrict__ idx,
    float* __restrict__ out, int batch)
{
    __shared__ alignas(16) int   sidx[4][32];
    __shared__ alignas(16) float sout[4][8];

    const int l    = (int)(threadIdx.x & 63);
    const int slot = (int)(threadIdx.x >> 6);
    const int h    = l >> 5;          // which element of each pair
    const int l5   = l & 31;
    const int wv   = blockIdx.x * 4 + slot;
    const int e0   = wv * EPW;
    if (e0 >= batch) return;
    const int lim = batch * 4 - 1;

    // one coalesced idx load per wave (32 lanes, one 128B segment) -> LDS
    if (l < 32) {
        int ia = e0 * 4 + l;
        ia = ia < lim ? ia : lim;
        sidx[slot][l] = idx[ia];
    }
    // same-wave DS write->read: in-order per wave (validated R8/R9)

    int4 iv[4];
    #pragma unroll
    for (int p = 0; p < 4; ++p)
        iv[p] = *reinterpret_cast<const int4*>(&sidx[slot][(2 * p + h) * 4]);

    // 16 dwordx4 loads, each covering 2 f16 rows (one per half-wave)
    const int r0 = l5 * 8;
    uint4 raw[4][4];
    #pragma unroll
    for (int p = 0; p < 4; ++p) {
        raw[p][0] = *reinterpret_cast<const uint4*>(wsh + 0 * FELEMS + (size_t)iv[p].x * RANK + r0);
        raw[p][1] = *reinterpret_cast<const uint4*>(wsh + 1 * FELEMS + (size_t)iv[p].y * RANK + r0);
        raw[p][2] = *reinterpret_cast<const uint4*>(wsh + 2 * FELEMS + (size_t)iv[p].z * RANK + r0);
        raw[p][3] = *reinterpret_cast<const uint4*>(wsh + 3 * FELEMS + (size_t)iv[p].w * RANK + r0);
    }

    float s[4];
    #pragma unroll
    for (int p = 0; p < 4; ++p) {
        float va[8], vb[8], vc[8], vd[8];
        cvt8(raw[p][0], va);
        cvt8(raw[p][1], vb);
        cvt8(raw[p][2], vc);
        cvt8(raw[p][3], vd);
        float acc = 0.f;
        #pragma unroll
        for (int k = 0; k < 8; ++k)
            acc += va[k] * vb[k] * vc[k] * vd[k];
        s[p] = acc;
    }

    // 5-step butterfly within each 32-lane half (4 independent chains)
    #pragma unroll
    for (int off = 16; off > 0; off >>= 1) {
        #pragma unroll
        for (int p = 0; p < 4; ++p)
            s[p] += __shfl_xor(s[p], off);
    }

    // repack via LDS -> one coalesced 8-lane store (32B segment)
    if (l5 == 0) {
        #pragma unroll
        for (int p = 0; p < 4; ++p)
            sout[slot][2 * p + h] = s[p];
    }
    if (l < 8) {
        const int e = e0 + l;
        if (e < batch) out[e] = sout[slot][l];
    }
}

// ---- fallback: R2 f32 direct gather (proven 21.4us) -----------------------
__global__ __launch_bounds__(256) void cp_gather_f32(
    const float* __restrict__ f0, const float* __restrict__ f1,
    const float* __restrict__ f2, const float* __restrict__ f3,
    const int*   __restrict__ idx,
    float*       __restrict__ out, int batch)
{
    const int wid  = (int)((blockIdx.x * blockDim.x + threadIdx.x) >> 6);
    const int lane = (int)(threadIdx.x & 63);
    const int e0   = wid * 4;
    if (e0 >= batch) return;
    const int r = lane * 4;
    float s[4];
    #pragma unroll
    for (int e = 0; e < 4; ++e) {
        const int  ec = (e0 + e) < batch ? (e0 + e) : batch - 1;
        const int4 iv = *reinterpret_cast<const int4*>(idx + (size_t)ec * 4);
        const float4 a = *reinterpret_cast<const float4*>(f0 + (size_t)iv.x * RANK + r);
        const float4 b = *reinterpret_cast<const float4*>(f1 + (size_t)iv.y * RANK + r);
        const float4 c = *reinterpret_cast<const float4*>(f2 + (size_t)iv.z * RANK + r);
        const float4 d = *reinterpret_cast<const float4*>(f3 + (size_t)iv.w * RANK + r);
        s[e] = a.x * b.x * c.x * d.x + a.y * b.y * c.y * d.y
             + a.z * b.z * c.z * d.z + a.w * b.w * c.w * d.w;
    }
    #pragma unroll
    for (int off = 32; off > 0; off >>= 1)
        #pragma unroll
        for (int e = 0; e < 4; ++e)
            s[e] += __shfl_xor(s[e], off);
    if (lane == 0)
        #pragma unroll
        for (int e = 0; e < 4; ++e)
            if (e0 + e < batch) out[e0 + e] = s[e];
}

extern "C" void kernel_launch(void* const* d_in, const int* in_sizes, int n_in,
                              void* d_out, int out_size, void* d_ws, size_t ws_size,
                              hipStream_t stream) {
    const float* f0  = (const float*)d_in[0];
    const float* f1  = (const float*)d_in[1];
    const float* f2  = (const float*)d_in[2];
    const float* f3  = (const float*)d_in[3];
    const int*   idx = (const int*)d_in[4];
    float* out = (float*)d_out;
    const int batch = out_size;

    const size_t ws_needed = (size_t)4 * FELEMS * sizeof(__half);  // 1 MiB
    if (ws_size >= ws_needed && batch >= 4) {
        __half* wsh = (__half*)d_ws;
        cp_convert_f16<<<dim3(FELEMS / (256 * 8), 4), 256, 0, stream>>>(f0, f1, f2, f3, wsh);
        const int waves = (batch + EPW - 1) / EPW;          // 12500
        const int grid  = (waves + 3) / 4;                  // 4 waves/block
        cp_gather_f16<<<grid, 256, 0, stream>>>(wsh, idx, out, batch);
    } else {
        const int grid = (batch + 15) / 16;
        cp_gather_f32<<<grid, 256, 0, stream>>>(f0, f1, f2, f3, idx, out, batch);
    }
}